// Round 1
// baseline (1107.707 us; speedup 1.0000x reference)
//
#include <hip/hip_runtime.h>
#include <type_traits>
#include <cstdint>
#include <cstddef>

#define L_SEQ 4800
#define DMODEL 256
#define BS 8
#define MROWS (BS*L_SEQ)          // 38400
#define PERBATCH (L_SEQ*DMODEL)   // 1228800
#define KVSET 67584               // 65536 KV + 2048 Ksum floats per mode

typedef __attribute__((ext_vector_type(8))) short bfrag8;
typedef __attribute__((ext_vector_type(4))) float floatx4;

// ---------- helpers ----------
__device__ __forceinline__ float bf2f(unsigned short u){
  union { unsigned int i; float f; } x; x.i = ((unsigned int)u) << 16; return x.f;
}
__device__ __forceinline__ unsigned short f2bf(float f){
  union { float f; unsigned int i; } x; x.f = f;
  x.i += 0x7fff + ((x.i >> 16) & 1);   // RNE
  return (unsigned short)(x.i >> 16);
}
__device__ __forceinline__ float phi(float x){
  return x > 0.f ? x + 1.f : __expf(x);
}
__device__ __forceinline__ void gll16(const void* g, void* l){
  __builtin_amdgcn_global_load_lds((const __attribute__((address_space(1))) unsigned int*)g,
      (__attribute__((address_space(3))) unsigned int*)l, 16, 0, 0);
}

// ---------- MFMA GEMM: C[M,N] = act(A[M,K] @ Bt[N,K]^T) (projections only) ----------
template<typename TC, bool RELU>
__global__ __launch_bounds__(256) void gemm_mfma(const unsigned short* __restrict__ A,
                                                 const unsigned short* __restrict__ Bt,
                                                 TC* __restrict__ C, int M, int N, int K){
  __shared__ unsigned short Al[128*32];   // [row][k]
  __shared__ unsigned short Bl[128*32];   // [col][k]
  const int tid  = threadIdx.x;
  const int lane = tid & 63;
  const int wave = tid >> 6;
  const int row0 = blockIdx.y << 7;
  const int col0 = blockIdx.x << 7;
  const int wr0  = (wave & 1) << 6;
  const int wc0  = (wave >> 1) << 6;

  floatx4 acc[4][4] = {};

  const int i0 = tid, i1 = tid + 256;
  const int r0 = i0 >> 2, s0 = i0 & 3;
  const int r1 = i1 >> 2, s1 = i1 & 3;
  const int m = lane & 15, q = lane >> 4;

  for (int k0 = 0; k0 < K; k0 += 32){
    const unsigned short* ga0 = A  + (size_t)(row0 + r0)*K + k0 + s0*8;
    const unsigned short* ga1 = A  + (size_t)(row0 + r1)*K + k0 + s1*8;
    const unsigned short* gb0 = Bt + (size_t)(col0 + r0)*K + k0 + s0*8;
    const unsigned short* gb1 = Bt + (size_t)(col0 + r1)*K + k0 + s1*8;
    gll16(ga0, Al + (size_t)i0*8);
    gll16(ga1, Al + (size_t)i1*8);
    gll16(gb0, Bl + (size_t)i0*8);
    gll16(gb1, Bl + (size_t)i1*8);
    __builtin_amdgcn_s_waitcnt(0);
    __syncthreads();

    bfrag8 af[4], bf[4];
    #pragma unroll
    for (int t = 0; t < 4; t++){
      af[t] = *(const bfrag8*)(Al + (size_t)(wr0 + t*16 + m)*32 + q*8);
      bf[t] = *(const bfrag8*)(Bl + (size_t)(wc0 + t*16 + m)*32 + q*8);
    }
    #pragma unroll
    for (int mt = 0; mt < 4; mt++)
      #pragma unroll
      for (int nt = 0; nt < 4; nt++)
        acc[mt][nt] = __builtin_amdgcn_mfma_f32_16x16x32_bf16(af[mt], bf[nt], acc[mt][nt], 0, 0, 0);
    __syncthreads();
  }

  #pragma unroll
  for (int mt = 0; mt < 4; mt++){
    #pragma unroll
    for (int nt = 0; nt < 4; nt++){
      const int col  = col0 + wc0 + nt*16 + m;
      const int rowb = row0 + wr0 + mt*16 + q*4;
      #pragma unroll
      for (int i = 0; i < 4; i++){
        float v = acc[mt][nt][i];
        if (RELU) v = v > 0.f ? v : 0.f;
        if constexpr (std::is_same<TC,float>::value) C[(size_t)(rowb+i)*N + col] = v;
        else                                         C[(size_t)(rowb+i)*N + col] = f2bf(v);
      }
    }
  }
}

// ---------- one-time converts ----------
__global__ __launch_bounds__(256) void wconv(const float* __restrict__ W, unsigned short* __restrict__ Wt,
                                             int kshift, int N){
  int idx = blockIdx.x*256 + threadIdx.x;
  int kk = idx & ((1 << kshift) - 1);
  int nn = idx >> kshift;
  Wt[idx] = f2bf(W[(size_t)kk*N + nn]);
}
__global__ __launch_bounds__(256) void conv_bf16(const float* __restrict__ in, unsigned short* __restrict__ out){
  int i = blockIdx.x*256 + threadIdx.x;
  float4 v = ((const float4*)in)[i];
  ushort4 o; o.x = f2bf(v.x); o.y = f2bf(v.y); o.z = f2bf(v.z); o.w = f2bf(v.w);
  ((ushort4*)out)[i] = o;
}

// ---------- permute materializers (coalesced both sides via LDS) ----------
__global__ __launch_bounds__(256) void permute1(const unsigned short* __restrict__ sA, unsigned short* __restrict__ dA,
                                                const unsigned short* __restrict__ sB, unsigned short* __restrict__ dB){
  const unsigned short* s = blockIdx.z ? sB : sA;
  unsigned short*       d = blockIdx.z ? dB : dA;
  __shared__ unsigned short tile[1024];
  const int t = threadIdx.x;
  const size_t base = (size_t)blockIdx.x * 1024;
  #pragma unroll
  for (int i = 0; i < 4; i++) tile[i*256 + t] = s[base + i*256 + t];
  __syncthreads();
  const int pg = ((t & 7) << 5) + (t >> 3);
  #pragma unroll
  for (int i = 0; i < 4; i++) d[base + i*256 + t] = tile[i*256 + pg];
}

__global__ __launch_bounds__(256) void permute2(const unsigned short* __restrict__ sA, unsigned short* __restrict__ dA,
                                                const unsigned short* __restrict__ sB, unsigned short* __restrict__ dB){
  const unsigned short* s = blockIdx.z ? sB : sA;
  unsigned short*       d = blockIdx.z ? dB : dA;
  __shared__ unsigned short tile[64*256];
  const int t = threadIdx.x;
  const int rr0 = blockIdx.x * 64;
  const size_t boff = (size_t)blockIdx.y * PERBATCH;
  #pragma unroll
  for (int i = 0; i < 16; i++){
    int u = i*256 + t;
    *(ushort4*)&tile[u*4] = *(const ushort4*)&s[boff + (size_t)rr0*256 + (size_t)u*4];
  }
  __syncthreads();
  #pragma unroll
  for (int i = 0; i < 8; i++){
    #pragma unroll
    for (int w = 0; w < 2; w++){
      int u = w*256 + t;
      int rr = u >> 3, c4 = (u & 7) << 2;
      ushort4 v = *(const ushort4*)&tile[rr*256 + i*32 + c4];
      *(ushort4*)&d[boff + (size_t)i*153600 + (size_t)rr0*32 + (size_t)u*4] = v;
    }
  }
}

__global__ __launch_bounds__(256) void permute3(const unsigned short* __restrict__ sA, unsigned short* __restrict__ dA,
                                                const unsigned short* __restrict__ sB, unsigned short* __restrict__ dB){
  const unsigned short* s = blockIdx.z ? sB : sA;
  unsigned short*       d = blockIdx.z ? dB : dA;
  __shared__ unsigned short tile[64*258];
  const int t = threadIdx.x;
  const int ll0 = blockIdx.x * 64;
  const size_t boff = (size_t)blockIdx.y * PERBATCH;
  #pragma unroll
  for (int i = 0; i < 32; i++){
    int u = i*256 + t;
    int row = u >> 7, col = (u & 127) << 1;
    *(ushort2*)&tile[row*258 + col] = *(const ushort2*)&s[boff + (size_t)(ll0+row)*256 + col];
  }
  __syncthreads();
  const int cw = t >> 6;
  const int ll = t & 63;
  #pragma unroll
  for (int cc = 0; cc < 256; cc += 4){
    int c = cc + cw;
    int sigma = ((c & 31) << 3) + (c >> 5);
    d[boff + (size_t)sigma*4800 + ll0 + ll] = tile[ll*258 + c];
  }
}

// ---------- attention phase A (contiguous) ----------
__global__ __launch_bounds__(256) void attn_stats(const unsigned short* __restrict__ kq,
                                                  const unsigned short* __restrict__ vq,
                                                  float* __restrict__ KV, float* __restrict__ Ksum){
  const int chunk = blockIdx.x, h = blockIdx.y, n = blockIdx.z;
  const int t = threadIdx.x;
  const int d = t >> 3;
  const int w4 = (t & 7) << 2;
  const size_t boff = (size_t)n * PERBATCH;
  __shared__ float kb[8][32], vb[8][32];
  const int lr = t >> 5, lj = t & 31;
  float a0=0.f, a1=0.f, a2=0.f, a3=0.f, ks=0.f;
  const int s0 = chunk * 240;
  for (int s = s0; s < s0 + 240; s += 8){
    int srci = (s + lr)*256 + (h << 5) + lj;
    kb[lr][lj] = phi(bf2f(kq[boff + srci]));
    vb[lr][lj] = bf2f(vq[boff + srci]);
    __syncthreads();
    #pragma unroll
    for (int r = 0; r < 8; r++){
      float kd = kb[r][d];
      ks += kd;
      a0 += kd * vb[r][w4+0];
      a1 += kd * vb[r][w4+1];
      a2 += kd * vb[r][w4+2];
      a3 += kd * vb[r][w4+3];
    }
    __syncthreads();
  }
  float* kvp = KV + (size_t)((((n<<3)+h)<<5) + d)*32 + w4;
  atomicAdd(kvp+0, a0);
  atomicAdd(kvp+1, a1);
  atomicAdd(kvp+2, a2);
  atomicAdd(kvp+3, a3);
  if ((t & 7) == 0) atomicAdd(Ksum + (((n<<3)+h)<<5) + d, ks);
}

// ---------- fused attention apply + Wm GEMM + LayerNorm -> hcat right half ----------
// grid (75, BS), 256 threads. 64 rows per block.
// LDS: kvs 32KB + msgL 32KB + pool 16KB = 80KB -> 2 blocks/CU.
__global__ __launch_bounds__(256) void attn_fused(const unsigned short* __restrict__ qq,
                                                  const float* __restrict__ KV,
                                                  const float* __restrict__ Ksum,
                                                  const unsigned short* __restrict__ WmT,
                                                  const float* __restrict__ g1,
                                                  const float* __restrict__ b1,
                                                  unsigned short* __restrict__ hcat){
  __shared__ float kvs[8192];     // [h][d][w] f32
  __shared__ char  msgL[32768];   // [64][256] bf16, 16B-unit XOR swizzle key=(row&7)<<4
  __shared__ char  pool[16384];   // phase A: Qs [8][256] f32 (8KB); phase B: WmS [256][32] bf16
  const int t = threadIdx.x;
  const int n = blockIdx.y;
  const int row0 = blockIdx.x << 6;
  const size_t boff = (size_t)n * PERBATCH;

  #pragma unroll
  for (int i = 0; i < 32; i++) kvs[i*256 + t] = KV[(size_t)n*8192 + i*256 + t];
  const float kssv = Ksum[n*256 + t];     // Ksum[h*32+w] with h=t>>5, w=t&31

  const int h = t >> 5, w = t & 31;
  const float* kvh = kvs + h*1024;
  float* Qs = (float*)pool;               // [8][256]

  // ---- phase A: msg = (phi(q)·KV) / (phi(q)·Ksum), 8 passes of 8 rows ----
  for (int p = 0; p < 8; p++){
    #pragma unroll
    for (int r = 0; r < 8; r++)
      Qs[r*256 + t] = phi(bf2f(qq[boff + (size_t)(row0 + p*8 + r)*256 + t]));
    __syncthreads();

    float acc[8], den[8];
    #pragma unroll
    for (int r = 0; r < 8; r++){
      float dd = Qs[r*256 + t] * kssv;        // per-lane term d=w
      #pragma unroll
      for (int o = 1; o < 32; o <<= 1) dd += __shfl_xor(dd, o, 64);
      den[r] = dd + 1e-6f;
      acc[r] = 0.f;
    }
    #pragma unroll
    for (int d4 = 0; d4 < 8; d4++){
      const float k0v = kvh[(d4*4+0)*32 + w];
      const float k1v = kvh[(d4*4+1)*32 + w];
      const float k2v = kvh[(d4*4+2)*32 + w];
      const float k3v = kvh[(d4*4+3)*32 + w];
      #pragma unroll
      for (int r = 0; r < 8; r++){
        float4 qv = *(const float4*)&Qs[r*256 + h*32 + d4*4];
        acc[r] += qv.x*k0v + qv.y*k1v + qv.z*k2v + qv.w*k3v;
      }
    }
    #pragma unroll
    for (int r = 0; r < 8; r++){
      int lrow = p*8 + r;
      int byte = (lrow << 9) + (t << 1);
      byte ^= (lrow & 7) << 4;
      *(unsigned short*)(msgL + byte) = f2bf(acc[r] / den[r]);
    }
    __syncthreads();
  }

  // ---- phase B: out[64][256] = msg @ WmT, LN, write hcat[:,256:512] ----
  const int wave = t >> 6, lane = t & 63, m = lane & 15, qd = lane >> 4;
  float gv[16], bv[16];
  #pragma unroll
  for (int nt = 0; nt < 16; nt++){ gv[nt] = g1[nt*16 + m]; bv[nt] = b1[nt*16 + m]; }

  floatx4 acc[16] = {};
  for (int ks = 0; ks < 8; ks++){
    const int k0 = ks << 5;
    #pragma unroll
    for (int i = 0; i < 4; i++){
      int u = (i << 8) + t;
      int c = u >> 2, q4 = u & 3;
      gll16(WmT + (size_t)c*256 + k0 + ((q4 ^ (c & 3)) << 3), pool + (u << 4));
    }
    asm volatile("s_waitcnt vmcnt(0)" ::: "memory");
    __builtin_amdgcn_s_barrier();
    asm volatile("" ::: "memory");
    const int arow = (wave << 4) + m;
    int abyte = (arow << 9) + (ks << 6) + (qd << 4);
    abyte ^= (m & 7) << 4;
    bfrag8 af = *(const bfrag8*)(msgL + abyte);
    #pragma unroll
    for (int nt = 0; nt < 16; nt++){
      int col = (nt << 4) + m;
      bfrag8 bf = *(const bfrag8*)(pool + col*64 + ((qd ^ (m & 3)) << 4));
      acc[nt] = __builtin_amdgcn_mfma_f32_16x16x32_bf16(af, bf, acc[nt], 0, 0, 0);
    }
    asm volatile("" ::: "memory");
    __builtin_amdgcn_s_barrier();
    asm volatile("" ::: "memory");
  }

  // LN fully in-wave (each wave owns rows 16*wave..+16, all 256 cols)
  float mu[4], rs[4];
  #pragma unroll
  for (int i = 0; i < 4; i++){
    float s = 0.f, q = 0.f;
    #pragma unroll
    for (int nt = 0; nt < 16; nt++){ float v = acc[nt][i]; s += v; q += v*v; }
    #pragma unroll
    for (int o = 1; o < 16; o <<= 1){ s += __shfl_xor(s, o, 64); q += __shfl_xor(q, o, 64); }
    float mean = s * (1.f/256.f);
    float var  = q * (1.f/256.f) - mean*mean;
    mu[i] = mean; rs[i] = rsqrtf(var + 1e-5f);
  }
  #pragma unroll
  for (int nt = 0; nt < 16; nt++){
    #pragma unroll
    for (int i = 0; i < 4; i++){
      int row = (wave << 4) + (qd << 2) + i;
      int col = (nt << 4) + m;
      int byte = (row << 9) + (col << 1);
      byte ^= (row & 7) << 4;
      *(unsigned short*)(msgL + byte) = f2bf((acc[nt][i] - mu[i]) * rs[i] * gv[nt] + bv[nt]);
    }
  }
  __syncthreads();
  const size_t gbase = (size_t)(n*4800 + row0) * 512;
  #pragma unroll
  for (int i = 0; i < 16; i++){
    int u = (i << 8) + t;
    int row = u >> 6, j = u & 63;
    int byte = ((row << 9) + (j << 3)) ^ ((row & 7) << 4);
    *(ushort4*)(hcat + gbase + (size_t)row*512 + 256 + (j << 2)) = *(const ushort4*)(msgL + byte);
  }
}

// ---------- fused FFN: macc (+)= LN(relu(hcat@W1)@W2) ----------
// grid (600), 512 threads (8 waves: 4 row-groups x 2 col-halves). 64 rows/block.
// LDS: stg 72KB (phase1: hcatS db 8KB + W1S db 64KB; phase2: W2S db 32KB + LN partials) + hid 64KB = 136KB.
__global__ __launch_bounds__(512) void ffn_fused(const unsigned short* __restrict__ hcat,
                                                 const unsigned short* __restrict__ W1T,
                                                 const unsigned short* __restrict__ W2T,
                                                 const float* __restrict__ g2,
                                                 const float* __restrict__ b2,
                                                 float* __restrict__ macc, int add){
  __shared__ char stg[73728];
  __shared__ char hidm[65536];   // phase: hid [64][512] bf16 swizzled; epilogue: y [64][256] f32
  const int tid = threadIdx.x;
  const int wave = tid >> 6, lane = tid & 63;
  const int rg = wave >> 1, ch = wave & 1;
  const int m = lane & 15, qd = lane >> 4;
  const int row0 = blockIdx.x << 6;

  float gv[8], bv[8];
  #pragma unroll
  for (int nt = 0; nt < 8; nt++){
    int col = (ch << 7) + nt*16 + m;
    gv[nt] = g2[col]; bv[nt] = b2[col];
  }

  // ---- phase 1: hid[64][512] = relu(hcat[64][512] @ W1) ----
  auto stage1 = [&](int ks, int b){
    const int k0 = ks << 5;
    {
      int u = tid & 255;                      // duplicated by upper waves (same data) -> uniform vmcnt
      int r = u >> 2, q4 = u & 3;
      gll16(hcat + (size_t)(row0 + r)*512 + k0 + ((q4 ^ (r & 3)) << 3),
            stg + (b << 12) + (u << 4));
    }
    #pragma unroll
    for (int i = 0; i < 4; i++){
      int u = (i << 9) + tid;
      int c = u >> 2, q4 = u & 3;
      gll16(W1T + (size_t)c*512 + k0 + ((q4 ^ (c & 3)) << 3),
            stg + 8192 + (b << 15) + (u << 4));
    }
  };

  floatx4 acc1[16] = {};
  stage1(0, 0);
  asm volatile("s_waitcnt vmcnt(0)" ::: "memory");
  __builtin_amdgcn_s_barrier();
  asm volatile("" ::: "memory");
  for (int ks = 0; ks < 16; ks++){
    if (ks < 15) stage1(ks+1, (ks+1) & 1);
    const char* hb = stg + ((ks & 1) << 12);
    const char* wb = stg + 8192 + ((ks & 1) << 15);
    const int arow = (rg << 4) + m;
    bfrag8 af = *(const bfrag8*)(hb + arow*64 + ((qd ^ (m & 3)) << 4));
    #pragma unroll
    for (int nt = 0; nt < 16; nt++){
      int col = (ch << 8) + (nt << 4) + m;
      bfrag8 bf = *(const bfrag8*)(wb + col*64 + ((qd ^ (m & 3)) << 4));
      acc1[nt] = __builtin_amdgcn_mfma_f32_16x16x32_bf16(af, bf, acc1[nt], 0, 0, 0);
    }
    asm volatile("" ::: "memory");
    if (ks < 15) asm volatile("s_waitcnt vmcnt(0)" ::: "memory");
    __builtin_amdgcn_s_barrier();
    asm volatile("" ::: "memory");
  }

  // relu + bf16 -> hid LDS (swizzled)
  #pragma unroll
  for (int nt = 0; nt < 16; nt++){
    #pragma unroll
    for (int i = 0; i < 4; i++){
      float v = acc1[nt][i];
      v = v > 0.f ? v : 0.f;
      int row = (rg << 4) + (qd << 2) + i;
      int col = (ch << 8) + (nt << 4) + m;
      int byte = (row << 10) + (col << 1);
      byte ^= (row & 7) << 4;
      *(unsigned short*)(hidm + byte) = f2bf(v);
    }
  }

  // ---- phase 2: out[64][256] = hid @ W2 ----
  auto stage2 = [&](int ks, int b){
    const int k0 = ks << 5;
    #pragma unroll
    for (int i = 0; i < 2; i++){
      int u = (i << 9) + tid;
      int c = u >> 2, q4 = u & 3;
      gll16(W2T + (size_t)c*512 + k0 + ((q4 ^ (c & 3)) << 3),
            stg + (b << 14) + (u << 4));
    }
  };
  stage2(0, 0);
  asm volatile("s_waitcnt vmcnt(0) lgkmcnt(0)" ::: "memory");
  __builtin_amdgcn_s_barrier();
  asm volatile("" ::: "memory");

  floatx4 acc2[8] = {};
  for (int ks = 0; ks < 16; ks++){
    if (ks < 15) stage2(ks+1, (ks+1) & 1);
    const char* wb = stg + ((ks & 1) << 14);
    const int arow = (rg << 4) + m;
    int abyte = (arow << 10) + (ks << 6) + (qd << 4);
    abyte ^= (m & 7) << 4;
    bfrag8 af = *(const bfrag8*)(hidm + abyte);
    #pragma unroll
    for (int nt = 0; nt < 8; nt++){
      int col = (ch << 7) + (nt << 4) + m;
      bfrag8 bf = *(const bfrag8*)(wb + col*64 + ((qd ^ (m & 3)) << 4));
      acc2[nt] = __builtin_amdgcn_mfma_f32_16x16x32_bf16(af, bf, acc2[nt], 0, 0, 0);
    }
    asm volatile("" ::: "memory");
    if (ks < 15) asm volatile("s_waitcnt vmcnt(0)" ::: "memory");
    __builtin_amdgcn_s_barrier();
    asm volatile("" ::: "memory");
  }

  // ---- LN epilogue (cross-wave partial merge over the 2 col-halves) ----
  float2* LNp = (float2*)(stg + 32768);   // [64][2] (sum, sumsq)
  #pragma unroll
  for (int i = 0; i < 4; i++){
    float s = 0.f, q = 0.f;
    #pragma unroll
    for (int nt = 0; nt < 8; nt++){ float v = acc2[nt][i]; s += v; q += v*v; }
    #pragma unroll
    for (int o = 1; o < 16; o <<= 1){ s += __shfl_xor(s, o, 64); q += __shfl_xor(q, o, 64); }
    if (m == 0){
      int row = (rg << 4) + (qd << 2) + i;
      LNp[row*2 + ch] = make_float2(s, q);
    }
  }
  asm volatile("s_waitcnt lgkmcnt(0)" ::: "memory");
  __builtin_amdgcn_s_barrier();
  asm volatile("" ::: "memory");

  float mu[4], rs[4];
  #pragma unroll
  for (int i = 0; i < 4; i++){
    int row = (rg << 4) + (qd << 2) + i;
    float2 a = LNp[row*2], c = LNp[row*2 + 1];
    float S = a.x + c.x, Q = a.y + c.y;
    float mean = S * (1.f/256.f);
    float var  = Q * (1.f/256.f) - mean*mean;
    mu[i] = mean; rs[i] = rsqrtf(var + 1e-5f);
  }
  float* ysh = (float*)hidm;    // [64][256] f32
  #pragma unroll
  for (int nt = 0; nt < 8; nt++){
    #pragma unroll
    for (int i = 0; i < 4; i++){
      int row = (rg << 4) + (qd << 2) + i;
      int col = (ch << 7) + (nt << 4) + m;
      ysh[(row << 8) + col] = (acc2[nt][i] - mu[i]) * rs[i] * gv[nt] + bv[nt];
    }
  }
  asm volatile("s_waitcnt lgkmcnt(0)" ::: "memory");
  __builtin_amdgcn_s_barrier();
  asm volatile("" ::: "memory");
  #pragma unroll
  for (int i = 0; i < 8; i++){
    int u = (i << 9) + tid;
    int row = u >> 6, c4 = u & 63;
    float4 v = *(const float4*)(ysh + (row << 8) + (c4 << 2));
    float4* gp = (float4*)(macc + (size_t)(row0 + row)*256) + c4;
    if (add){ float4 o = *gp; v.x += o.x; v.y += o.y; v.z += o.z; v.w += o.w; }
    *gp = v;
  }
}

// ---------- elementwise ----------
__global__ __launch_bounds__(256) void fill_hcat(const float* __restrict__ x, unsigned short* __restrict__ hcat){
  size_t i = (size_t)blockIdx.x*256 + threadIdx.x;
  hcat[(i >> 8)*512 + (i & 255)] = f2bf(x[i]);
}
__global__ __launch_bounds__(256) void xmid_k(const float* __restrict__ x, const float* __restrict__ macc,
                                              float* __restrict__ xmid, unsigned short* __restrict__ hcat){
  size_t i = (size_t)blockIdx.x*256 + threadIdx.x;
  float v = x[i] + 0.5f*macc[i];
  xmid[i] = v;
  hcat[(i >> 8)*512 + (i & 255)] = f2bf(v);
}
__global__ __launch_bounds__(256) void final_k(float* __restrict__ out, const float* __restrict__ macc){
  size_t i = (size_t)blockIdx.x*256 + threadIdx.x;
  out[i] = out[i] + 0.5f*macc[i];
}
__global__ __launch_bounds__(256) void zero_k(float* __restrict__ p, int n){
  int i = blockIdx.x*256 + threadIdx.x;
  if (i < n) p[i] = 0.f;
}

// ---------- orchestration ----------
extern "C" void kernel_launch(void* const* d_in, const int* in_sizes, int n_in,
                              void* d_out, int out_size, void* d_ws, size_t ws_size,
                              hipStream_t stream){
  const float* x   = (const float*)d_in[0];
  const float* src = (const float*)d_in[1];
  const float* Wq  = (const float*)d_in[2];
  const float* Wk  = (const float*)d_in[3];
  const float* Wv  = (const float*)d_in[4];
  const float* Wm  = (const float*)d_in[5];
  const float* W1  = (const float*)d_in[6];
  const float* W2  = (const float*)d_in[7];
  const float* g1  = (const float*)d_in[8];
  const float* b1  = (const float*)d_in[9];
  const float* g2  = (const float*)d_in[10];
  const float* b2  = (const float*)d_in[11];
  float* out = (float*)d_out;

  // ---- workspace layout ----
  char* ws = (char*)d_ws;
  size_t off = 0;
  auto alloc = [&](size_t bytes) -> void* {
    void* p = ws + off;
    off += (bytes + 255) & ~(size_t)255;
    return p;
  };
  unsigned short* qB    = (unsigned short*)alloc((size_t)MROWS*256*2);
  unsigned short* kB    = (unsigned short*)alloc((size_t)MROWS*256*2);
  unsigned short* vB    = (unsigned short*)alloc((size_t)MROWS*256*2);
  unsigned short* hcatB = (unsigned short*)alloc((size_t)MROWS*512*2);
  float* t1   = (float*)alloc((size_t)MROWS*256*4);
  float* macc = (float*)alloc((size_t)MROWS*256*4);
  float* KV4  = (float*)alloc((size_t)4*KVSET*4);
  unsigned short* WqT = (unsigned short*)alloc((size_t)256*256*2);
  unsigned short* WkT = (unsigned short*)alloc((size_t)256*256*2);
  unsigned short* WvT = (unsigned short*)alloc((size_t)256*256*2);
  unsigned short* WmT = (unsigned short*)alloc((size_t)256*256*2);
  unsigned short* W1T = (unsigned short*)alloc((size_t)512*512*2);
  unsigned short* W2T = (unsigned short*)alloc((size_t)256*512*2);
  (void)ws_size; (void)in_sizes; (void)n_in; (void)out_size;

  unsigned short* srcbf = (unsigned short*)t1;
  unsigned short* xbf   = srcbf + (size_t)MROWS*256;
  unsigned short* qP    = (unsigned short*)t1;
  unsigned short* kP    = (unsigned short*)macc;
  unsigned short* vP    = kP + (size_t)MROWS*256;
  float* xmid = out;

  const dim3 blk(256);

  // one-time converts
  wconv<<<dim3(256),  blk, 0, stream>>>(Wq, WqT, 8, 256);
  wconv<<<dim3(256),  blk, 0, stream>>>(Wk, WkT, 8, 256);
  wconv<<<dim3(256),  blk, 0, stream>>>(Wv, WvT, 8, 256);
  wconv<<<dim3(256),  blk, 0, stream>>>(Wm, WmT, 8, 256);
  wconv<<<dim3(1024), blk, 0, stream>>>(W1, W1T, 9, 512);
  wconv<<<dim3(512),  blk, 0, stream>>>(W2, W2T, 9, 256);
  conv_bf16<<<dim3(9600), blk, 0, stream>>>(src, srcbf);
  conv_bf16<<<dim3(9600), blk, 0, stream>>>(x,   xbf);

  // projections
  gemm_mfma<unsigned short, false><<<dim3(2,300), blk, 0, stream>>>(xbf,   WqT, qB, MROWS, 256, 256);
  gemm_mfma<unsigned short, false><<<dim3(2,300), blk, 0, stream>>>(srcbf, WkT, kB, MROWS, 256, 256);
  gemm_mfma<unsigned short, false><<<dim3(2,300), blk, 0, stream>>>(srcbf, WvT, vB, MROWS, 256, 256);

  // all-mode stats upfront; permuted k/v in macc space
  zero_k<<<dim3(1056), blk, 0, stream>>>(KV4, 4*KVSET);
  attn_stats<<<dim3(20,8,8), blk, 0, stream>>>(kB, vB, KV4 + 0*KVSET, KV4 + 0*KVSET + 65536);
  permute1<<<dim3(9600,1,2), blk, 0, stream>>>(kB, kP, vB, vP);
  attn_stats<<<dim3(20,8,8), blk, 0, stream>>>(kP, vP, KV4 + 1*KVSET, KV4 + 1*KVSET + 65536);
  permute2<<<dim3(75,8,2),  blk, 0, stream>>>(kB, kP, vB, vP);
  attn_stats<<<dim3(20,8,8), blk, 0, stream>>>(kP, vP, KV4 + 2*KVSET, KV4 + 2*KVSET + 65536);
  permute3<<<dim3(75,8,2),  blk, 0, stream>>>(kB, kP, vB, vP);
  attn_stats<<<dim3(20,8,8), blk, 0, stream>>>(kP, vP, KV4 + 3*KVSET, KV4 + 3*KVSET + 65536);

  fill_hcat<<<dim3(MROWS), blk, 0, stream>>>(x, hcatB);

  auto run_block = [&](int mode, int add){
    const float* KV   = KV4 + (size_t)mode*KVSET;
    const float* Ksum = KV + 65536;
    const unsigned short* qsrc = qB;
    if (mode == 1){ permute1<<<dim3(9600,1,1), blk, 0, stream>>>(qB, qP, nullptr, nullptr); qsrc = qP; }
    else if (mode == 2){ permute2<<<dim3(75,8,1), blk, 0, stream>>>(qB, qP, nullptr, nullptr); qsrc = qP; }
    else if (mode == 3){ permute3<<<dim3(75,8,1), blk, 0, stream>>>(qB, qP, nullptr, nullptr); qsrc = qP; }
    attn_fused<<<dim3(75,BS), blk, 0, stream>>>(qsrc, KV, Ksum, WmT, g1, b1, hcatB);
    ffn_fused<<<dim3(600), dim3(512), 0, stream>>>(hcatB, W1T, W2T, g2, b2, macc, add);
  };

  run_block(0, 0);   // m   (identity)
  run_block(1, 1);   // m3  (p13)
  xmid_k<<<dim3(MROWS), blk, 0, stream>>>(x, macc, xmid, hcatB);
  run_block(2, 0);   // m1  (p21)
  run_block(3, 1);   // m2  (p32)
  final_k<<<dim3(MROWS), blk, 0, stream>>>(out, macc);
}